// Round 1
// baseline (591.915 us; speedup 1.0000x reference)
//
#include <hip/hip_runtime.h>
#include <hip/hip_bf16.h>
#include <math.h>

#define NN 256
#define CC 128
#define HH 4
#define DD 32

typedef uint4 u128;

// ---------------------------------------------------------------------------
// K1: qkv = pair_rep @ Wqkv + bqkv   (fp32 compute, bf16 output)
// A: [65536,128] fp32, B: [128,384] fp32, out: [65536,384] bf16
// 64x64 tile, 256 threads, each thread 4x4.
// ---------------------------------------------------------------------------
__global__ __launch_bounds__(256) void qkv_gemm_kernel(
    const float* __restrict__ A, const float* __restrict__ B,
    const float* __restrict__ bias, __hip_bfloat16* __restrict__ out)
{
    __shared__ float As[64][132];   // pad 132 -> 2-way max (free)
    __shared__ float Bs[128][64];
    const int t = threadIdx.x;
    const int m0 = blockIdx.x * 64;
    const int n0 = blockIdx.y * 64;

    #pragma unroll
    for (int it = 0; it < 8; ++it) {            // A tile: 64x128 = 2048 float4
        int idx = it * 256 + t;
        int r = idx >> 5, c4 = (idx & 31) * 4;
        float4 v = *(const float4*)(A + (size_t)(m0 + r) * CC + c4);
        *(float4*)&As[r][c4] = v;
    }
    #pragma unroll
    for (int it = 0; it < 8; ++it) {            // B tile: 128x64 = 2048 float4
        int idx = it * 256 + t;
        int kr = idx >> 4, c4 = (idx & 15) * 4;
        *(float4*)&Bs[kr][c4] = *(const float4*)(B + (size_t)kr * 384 + n0 + c4);
    }
    __syncthreads();

    const int tx = t & 15, ty = t >> 4;
    const int r0 = ty * 4, c0 = tx * 4;
    float acc[4][4];
    #pragma unroll
    for (int i = 0; i < 4; ++i)
        #pragma unroll
        for (int j = 0; j < 4; ++j) acc[i][j] = 0.f;

    #pragma unroll 4
    for (int k = 0; k < CC; ++k) {
        float4 b = *(float4*)&Bs[k][c0];
        float a0 = As[r0][k], a1 = As[r0 + 1][k], a2 = As[r0 + 2][k], a3 = As[r0 + 3][k];
        acc[0][0] += a0 * b.x; acc[0][1] += a0 * b.y; acc[0][2] += a0 * b.z; acc[0][3] += a0 * b.w;
        acc[1][0] += a1 * b.x; acc[1][1] += a1 * b.y; acc[1][2] += a1 * b.z; acc[1][3] += a1 * b.w;
        acc[2][0] += a2 * b.x; acc[2][1] += a2 * b.y; acc[2][2] += a2 * b.z; acc[2][3] += a2 * b.w;
        acc[3][0] += a3 * b.x; acc[3][1] += a3 * b.y; acc[3][2] += a3 * b.z; acc[3][3] += a3 * b.w;
    }

    #pragma unroll
    for (int i = 0; i < 4; ++i) {
        int m = m0 + r0 + i;
        #pragma unroll
        for (int j = 0; j < 4; ++j) {
            int n = n0 + c0 + j;
            out[(size_t)m * 384 + n] = __float2bfloat16(acc[i][j] + bias[n]);
        }
    }
}

// ---------------------------------------------------------------------------
// K2: attention. One block (256 thr = 4 waves) per (i,h).
//   scores[j,k] = q[i,j,h,:].k[i,k,h,:]/sqrt(32) + dscale*dm[j,k]; mask[j,k]->-inf
//   softmax over k; out[i,j,h,:] = attn @ v
// ---------------------------------------------------------------------------
__global__ __launch_bounds__(256) void attn_kernel(
    const __hip_bfloat16* __restrict__ qkv,   // [65536,384]
    const float* __restrict__ dm,             // [256,256]
    const int* __restrict__ mask,             // [256,256]
    const float* __restrict__ dscale_p,       // [1]
    __hip_bfloat16* __restrict__ attn_out)    // [65536,128]
{
    __shared__ __hip_bfloat16 KsT[DD][2 * NN + 2];  // transposed, stride 258 bf16 = 129 dwords (odd -> conflict-free)
    __shared__ __hip_bfloat16 Vs[NN][DD];           // row-major
    __shared__ __hip_bfloat16 Qs[NN][DD];
    __shared__ float Ps[4][NN];

    const int bi = blockIdx.x;
    const int i = bi >> 2, h = bi & 3;
    const int t = threadIdx.x;
    const float dsc = dscale_p[0];
    const float scale = 0.17677669529663687f;   // 1/sqrt(32)

    // stage: thread t handles row t of q/k/v for this (i,h)
    {
        const __hip_bfloat16* base = qkv + (size_t)(i * NN + t) * 384 + h * DD;
        const u128* qsrc = (const u128*)base;
        const u128* ksrc = (const u128*)(base + CC);
        const u128* vsrc = (const u128*)(base + 2 * CC);
        u128* qdst = (u128*)&Qs[t][0];
        u128* vdst = (u128*)&Vs[t][0];
        u128 kr[4];
        #pragma unroll
        for (int u = 0; u < 4; ++u) { qdst[u] = qsrc[u]; kr[u] = ksrc[u]; vdst[u] = vsrc[u]; }
        const __hip_bfloat16* kv = (const __hip_bfloat16*)kr;
        #pragma unroll
        for (int d = 0; d < DD; ++d) KsT[d][t] = kv[d];
    }
    __syncthreads();

    const int w = t >> 6;
    const int lane = t & 63;

    for (int jt = 0; jt < NN / 4; ++jt) {
        const int j = jt * 4 + w;

        // broadcast-load q row into registers
        float q[DD];
        {
            const u128* qs = (const u128*)&Qs[j][0];
            #pragma unroll
            for (int u = 0; u < 4; ++u) {
                u128 x = qs[u];
                const __hip_bfloat16* qh = (const __hip_bfloat16*)&x;
                #pragma unroll
                for (int e = 0; e < 8; ++e) q[u * 8 + e] = __bfloat162float(qh[e]);
            }
        }

        // scores: lane owns kk = {2*lane, 2*lane+1, 128+2*lane, 129+2*lane}
        float s[4];
        {
            float a0x = 0.f, a0y = 0.f, a1x = 0.f, a1y = 0.f;
            #pragma unroll
            for (int d = 0; d < DD; ++d) {
                float qd = q[d];
                __hip_bfloat162 k0 = *(const __hip_bfloat162*)&KsT[d][2 * lane];
                __hip_bfloat162 k1 = *(const __hip_bfloat162*)&KsT[d][2 * lane + 128];
                a0x += qd * __bfloat162float(k0.x);
                a0y += qd * __bfloat162float(k0.y);
                a1x += qd * __bfloat162float(k1.x);
                a1y += qd * __bfloat162float(k1.y);
            }
            const float* dmrow = dm + (size_t)j * NN;
            const int* mrow = mask + (size_t)j * NN;
            int kA = 2 * lane, kB = 128 + 2 * lane;
            s[0] = mrow[kA]     ? -INFINITY : a0x * scale + dsc * dmrow[kA];
            s[1] = mrow[kA + 1] ? -INFINITY : a0y * scale + dsc * dmrow[kA + 1];
            s[2] = mrow[kB]     ? -INFINITY : a1x * scale + dsc * dmrow[kB];
            s[3] = mrow[kB + 1] ? -INFINITY : a1y * scale + dsc * dmrow[kB + 1];
        }

        // softmax over 256 values (4/lane x 64 lanes)
        float m = fmaxf(fmaxf(s[0], s[1]), fmaxf(s[2], s[3]));
        #pragma unroll
        for (int off = 32; off > 0; off >>= 1) m = fmaxf(m, __shfl_xor(m, off, 64));
        float e0 = __expf(s[0] - m), e1 = __expf(s[1] - m);
        float e2 = __expf(s[2] - m), e3 = __expf(s[3] - m);
        float l = e0 + e1 + e2 + e3;
        #pragma unroll
        for (int off = 32; off > 0; off >>= 1) l += __shfl_xor(l, off, 64);

        {
            int kA = 2 * lane, kB = 128 + 2 * lane;
            Ps[w][kA] = e0; Ps[w][kA + 1] = e1;
            Ps[w][kB] = e2; Ps[w][kB + 1] = e3;
        }

        // PV: lane owns d-pair dp=lane&15 (d=2dp,2dp+1), quarter qt=lane>>4,
        // kk = it*4+qt (interleaved -> conflict-free Vs bf162 reads)
        const int dp = lane & 15;
        const int qt = lane >> 4;
        float ax = 0.f, ay = 0.f;
        const float* pw = Ps[w];
        #pragma unroll 8
        for (int it = 0; it < 64; ++it) {
            int kk = it * 4 + qt;
            float p = pw[kk];
            __hip_bfloat162 vv = *(const __hip_bfloat162*)&Vs[kk][2 * dp];
            ax += p * __bfloat162float(vv.x);
            ay += p * __bfloat162float(vv.y);
        }
        ax += __shfl_xor(ax, 16, 64); ay += __shfl_xor(ay, 16, 64);
        ax += __shfl_xor(ax, 32, 64); ay += __shfl_xor(ay, 32, 64);
        if (lane < 16) {
            float inv = 1.0f / l;
            __hip_bfloat162 o;
            o.x = __float2bfloat16(ax * inv);
            o.y = __float2bfloat16(ay * inv);
            *(__hip_bfloat162*)&attn_out[(size_t)(i * NN + j) * CC + h * DD + 2 * dp] = o;
        }
    }
}

// ---------------------------------------------------------------------------
// K3: out = attn_out @ Wout + bout   (bf16 A, fp32 B/out)
// ---------------------------------------------------------------------------
__global__ __launch_bounds__(256) void out_gemm_kernel(
    const __hip_bfloat16* __restrict__ A, const float* __restrict__ B,
    const float* __restrict__ bias, float* __restrict__ out)
{
    __shared__ float As[64][132];
    __shared__ float Bs[128][64];
    const int t = threadIdx.x;
    const int m0 = blockIdx.x * 64;
    const int n0 = blockIdx.y * 64;

    #pragma unroll
    for (int it = 0; it < 4; ++it) {            // A tile: 64x128 bf16 = 1024 u128
        int idx = it * 256 + t;
        int r = idx >> 4, c8 = (idx & 15) * 8;
        u128 raw = *(const u128*)(A + (size_t)(m0 + r) * CC + c8);
        const __hip_bfloat16* hb = (const __hip_bfloat16*)&raw;
        #pragma unroll
        for (int e = 0; e < 8; ++e) As[r][c8 + e] = __bfloat162float(hb[e]);
    }
    #pragma unroll
    for (int it = 0; it < 8; ++it) {            // B tile: 128x64
        int idx = it * 256 + t;
        int kr = idx >> 4, c4 = (idx & 15) * 4;
        *(float4*)&Bs[kr][c4] = *(const float4*)(B + (size_t)kr * CC + n0 + c4);
    }
    __syncthreads();

    const int tx = t & 15, ty = t >> 4;
    const int r0 = ty * 4, c0 = tx * 4;
    float acc[4][4];
    #pragma unroll
    for (int i = 0; i < 4; ++i)
        #pragma unroll
        for (int j = 0; j < 4; ++j) acc[i][j] = 0.f;

    #pragma unroll 4
    for (int k = 0; k < CC; ++k) {
        float4 b = *(float4*)&Bs[k][c0];
        float a0 = As[r0][k], a1 = As[r0 + 1][k], a2 = As[r0 + 2][k], a3 = As[r0 + 3][k];
        acc[0][0] += a0 * b.x; acc[0][1] += a0 * b.y; acc[0][2] += a0 * b.z; acc[0][3] += a0 * b.w;
        acc[1][0] += a1 * b.x; acc[1][1] += a1 * b.y; acc[1][2] += a1 * b.z; acc[1][3] += a1 * b.w;
        acc[2][0] += a2 * b.x; acc[2][1] += a2 * b.y; acc[2][2] += a2 * b.z; acc[2][3] += a2 * b.w;
        acc[3][0] += a3 * b.x; acc[3][1] += a3 * b.y; acc[3][2] += a3 * b.z; acc[3][3] += a3 * b.w;
    }

    #pragma unroll
    for (int i = 0; i < 4; ++i) {
        int m = m0 + r0 + i;
        #pragma unroll
        for (int j = 0; j < 4; ++j) {
            int n = n0 + c0 + j;
            out[(size_t)m * CC + n] = acc[i][j] + bias[n];
        }
    }
}

// ---------------------------------------------------------------------------
extern "C" void kernel_launch(void* const* d_in, const int* in_sizes, int n_in,
                              void* d_out, int out_size, void* d_ws, size_t ws_size,
                              hipStream_t stream) {
    const float* pair_rep = (const float*)d_in[0];
    const float* dm       = (const float*)d_in[1];
    const float* Wqkv     = (const float*)d_in[2];
    const float* bqkv     = (const float*)d_in[3];
    const float* Wout     = (const float*)d_in[4];
    const float* bout     = (const float*)d_in[5];
    const float* dscale   = (const float*)d_in[6];
    const int*   mask     = (const int*)d_in[7];
    float* out = (float*)d_out;

    __hip_bfloat16* qkv  = (__hip_bfloat16*)d_ws;                   // 65536*384 bf16 = 48 MB
    __hip_bfloat16* attn = qkv + (size_t)65536 * 384;               // 65536*128 bf16 = 16 MB

    dim3 blk(256);
    qkv_gemm_kernel<<<dim3(1024, 6), blk, 0, stream>>>(pair_rep, Wqkv, bqkv, qkv);
    attn_kernel<<<dim3(1024), blk, 0, stream>>>(qkv, dm, mask, dscale, attn);
    out_gemm_kernel<<<dim3(1024, 2), blk, 0, stream>>>(attn, Wout, bout, out);
}

// Round 2
// 258.878 us; speedup vs baseline: 2.2865x; 2.2865x over previous
//
#include <hip/hip_runtime.h>
#include <hip/hip_bf16.h>
#include <math.h>

#define NN 256
#define CC 128
#define HH 4
#define DD 32

typedef uint4 u128;
typedef __bf16 bf16x8 __attribute__((ext_vector_type(8)));
typedef float f32x4 __attribute__((ext_vector_type(4)));

// ---------------------------------------------------------------------------
// K0: biasM[j,k] = mask[j,k] ? -inf : dscale*dm[j,k]   (shared by all (i,h))
// ---------------------------------------------------------------------------
__global__ __launch_bounds__(256) void bias_kernel(
    const float* __restrict__ dm, const int* __restrict__ mask,
    const float* __restrict__ dscale, float* __restrict__ biasM)
{
    int idx = blockIdx.x * 256 + threadIdx.x;
    biasM[idx] = mask[idx] ? -INFINITY : dscale[0] * dm[idx];
}

// ---------------------------------------------------------------------------
// K1: qkv = pair_rep @ Wqkv + bqkv   (fp32 compute, bf16 output)
// ---------------------------------------------------------------------------
__global__ __launch_bounds__(256) void qkv_gemm_kernel(
    const float* __restrict__ A, const float* __restrict__ B,
    const float* __restrict__ bias, __hip_bfloat16* __restrict__ out)
{
    __shared__ float As[64][132];
    __shared__ float Bs[128][64];
    const int t = threadIdx.x;
    const int m0 = blockIdx.x * 64;
    const int n0 = blockIdx.y * 64;

    #pragma unroll
    for (int it = 0; it < 8; ++it) {
        int idx = it * 256 + t;
        int r = idx >> 5, c4 = (idx & 31) * 4;
        float4 v = *(const float4*)(A + (size_t)(m0 + r) * CC + c4);
        *(float4*)&As[r][c4] = v;
    }
    #pragma unroll
    for (int it = 0; it < 8; ++it) {
        int idx = it * 256 + t;
        int kr = idx >> 4, c4 = (idx & 15) * 4;
        *(float4*)&Bs[kr][c4] = *(const float4*)(B + (size_t)kr * 384 + n0 + c4);
    }
    __syncthreads();

    const int tx = t & 15, ty = t >> 4;
    const int r0 = ty * 4, c0 = tx * 4;
    float acc[4][4];
    #pragma unroll
    for (int i = 0; i < 4; ++i)
        #pragma unroll
        for (int j = 0; j < 4; ++j) acc[i][j] = 0.f;

    #pragma unroll 4
    for (int k = 0; k < CC; ++k) {
        float4 b = *(float4*)&Bs[k][c0];
        float a0 = As[r0][k], a1 = As[r0 + 1][k], a2 = As[r0 + 2][k], a3 = As[r0 + 3][k];
        acc[0][0] += a0 * b.x; acc[0][1] += a0 * b.y; acc[0][2] += a0 * b.z; acc[0][3] += a0 * b.w;
        acc[1][0] += a1 * b.x; acc[1][1] += a1 * b.y; acc[1][2] += a1 * b.z; acc[1][3] += a1 * b.w;
        acc[2][0] += a2 * b.x; acc[2][1] += a2 * b.y; acc[2][2] += a2 * b.z; acc[2][3] += a2 * b.w;
        acc[3][0] += a3 * b.x; acc[3][1] += a3 * b.y; acc[3][2] += a3 * b.z; acc[3][3] += a3 * b.w;
    }

    #pragma unroll
    for (int i = 0; i < 4; ++i) {
        int m = m0 + r0 + i;
        #pragma unroll
        for (int j = 0; j < 4; ++j) {
            int n = n0 + c0 + j;
            out[(size_t)m * 384 + n] = __float2bfloat16(acc[i][j] + bias[n]);
        }
    }
}

// ---------------------------------------------------------------------------
// K2: MFMA attention. One block (4 waves) per (i,h); wave w owns j-rows
// [w*64, w*64+64) as four 16-row tiles.
//   QK^T: A-frag = Q from global, B-frag = K from LDS (stride 40 -> 2-way free)
//   softmax in C-layout (row=quad*4+reg, col=lane&15), shfl within quad
//   P -> LDS (A-operand layout), PV vs V^T in LDS
// ---------------------------------------------------------------------------
__global__ __launch_bounds__(256) void attn_mfma_kernel(
    const __hip_bfloat16* __restrict__ qkv,   // [65536,384]
    const float* __restrict__ biasM,          // [256,256]
    __hip_bfloat16* __restrict__ attn_out)    // [65536,128]
{
    __shared__ __align__(16) __hip_bfloat16 Ks[NN][40];      // K rows (80B stride)
    __shared__ __align__(16) __hip_bfloat16 VTs[DD][264];    // V^T (528B stride)
    __shared__ __align__(16) __hip_bfloat16 Ps[4][16][264];  // per-wave P tile

    const int bi = blockIdx.x;
    const int i = bi >> 2, h = bi & 3;
    const int t = threadIdx.x;
    const float scale = 0.17677669529663687f;   // 1/sqrt(32)

    // stage K row t (row-major) and V row t (transposed)
    {
        const __hip_bfloat16* base = qkv + (size_t)(i * NN + t) * 384 + h * DD;
        const u128* ksrc = (const u128*)(base + CC);
        const u128* vsrc = (const u128*)(base + 2 * CC);
        u128* kdst = (u128*)&Ks[t][0];
        u128 vr[4];
        #pragma unroll
        for (int u = 0; u < 4; ++u) { kdst[u] = ksrc[u]; vr[u] = vsrc[u]; }
        const __hip_bfloat16* vh = (const __hip_bfloat16*)vr;
        #pragma unroll
        for (int d = 0; d < DD; ++d) VTs[d][t] = vh[d];
    }
    __syncthreads();

    const int w = t >> 6, lane = t & 63;
    const int n16 = lane & 15, quad = lane >> 4;

    for (int jt = 0; jt < 4; ++jt) {
        const int j0 = w * 64 + jt * 16;

        // A-frag: Q[j0+m][quad*8..+8] direct from global (16B aligned)
        bf16x8 qa = *(const bf16x8*)(qkv + (size_t)(i * NN + j0 + n16) * 384 + h * DD + quad * 8);

        // S = Q K^T : 16 independent MFMAs
        f32x4 s[16];
        #pragma unroll
        for (int kt = 0; kt < 16; ++kt) {
            bf16x8 kb = *(const bf16x8*)&Ks[kt * 16 + n16][quad * 8];
            s[kt] = __builtin_amdgcn_mfma_f32_16x16x32_bf16(qa, kb, (f32x4){0.f, 0.f, 0.f, 0.f}, 0, 0, 0);
        }

        // bias + softmax per row (lane's rows: j0 + quad*4 + r)
        float inv_sum[4];
        #pragma unroll
        for (int r = 0; r < 4; ++r) {
            const float* brow = biasM + (size_t)(j0 + quad * 4 + r) * NN + n16;
            float m = -INFINITY;
            #pragma unroll
            for (int kt = 0; kt < 16; ++kt) {
                float v = s[kt][r] * scale + brow[kt * 16];
                s[kt][r] = v;
                m = fmaxf(m, v);
            }
            m = fmaxf(m, __shfl_xor(m, 1));
            m = fmaxf(m, __shfl_xor(m, 2));
            m = fmaxf(m, __shfl_xor(m, 4));
            m = fmaxf(m, __shfl_xor(m, 8));
            float sum = 0.f;
            #pragma unroll
            for (int kt = 0; kt < 16; ++kt) {
                float p = __expf(s[kt][r] - m);
                sum += p;
                Ps[w][quad * 4 + r][kt * 16 + n16] = __float2bfloat16(p);
            }
            sum += __shfl_xor(sum, 1);
            sum += __shfl_xor(sum, 2);
            sum += __shfl_xor(sum, 4);
            sum += __shfl_xor(sum, 8);
            inv_sum[r] = 1.0f / sum;
        }

        // O = P V : A-frag = P rows (m=n16), B-frag = V^T rows (n=d)
        f32x4 o[2] = {(f32x4){0.f, 0.f, 0.f, 0.f}, (f32x4){0.f, 0.f, 0.f, 0.f}};
        #pragma unroll
        for (int c = 0; c < 8; ++c) {
            bf16x8 pa = *(const bf16x8*)&Ps[w][n16][c * 32 + quad * 8];
            #pragma unroll
            for (int dt = 0; dt < 2; ++dt) {
                bf16x8 vb = *(const bf16x8*)&VTs[dt * 16 + n16][c * 32 + quad * 8];
                o[dt] = __builtin_amdgcn_mfma_f32_16x16x32_bf16(pa, vb, o[dt], 0, 0, 0);
            }
        }

        // write: row j0+quad*4+r, col dt*16+n16
        #pragma unroll
        for (int r = 0; r < 4; ++r) {
            __hip_bfloat16* orow = attn_out + (size_t)(i * NN + j0 + quad * 4 + r) * CC + h * DD;
            #pragma unroll
            for (int dt = 0; dt < 2; ++dt)
                orow[dt * 16 + n16] = __float2bfloat16(o[dt][r] * inv_sum[r]);
        }
    }
}

// ---------------------------------------------------------------------------
// K3: out = attn_out @ Wout + bout   (bf16 A, fp32 B/out)
// ---------------------------------------------------------------------------
__global__ __launch_bounds__(256) void out_gemm_kernel(
    const __hip_bfloat16* __restrict__ A, const float* __restrict__ B,
    const float* __restrict__ bias, float* __restrict__ out)
{
    __shared__ float As[64][132];
    __shared__ float Bs[128][64];
    const int t = threadIdx.x;
    const int m0 = blockIdx.x * 64;
    const int n0 = blockIdx.y * 64;

    #pragma unroll
    for (int it = 0; it < 4; ++it) {
        int idx = it * 256 + t;
        int r = idx >> 4, c8 = (idx & 15) * 8;
        u128 raw = *(const u128*)(A + (size_t)(m0 + r) * CC + c8);
        const __hip_bfloat16* hb = (const __hip_bfloat16*)&raw;
        #pragma unroll
        for (int e = 0; e < 8; ++e) As[r][c8 + e] = __bfloat162float(hb[e]);
    }
    #pragma unroll
    for (int it = 0; it < 8; ++it) {
        int idx = it * 256 + t;
        int kr = idx >> 4, c4 = (idx & 15) * 4;
        *(float4*)&Bs[kr][c4] = *(const float4*)(B + (size_t)kr * CC + n0 + c4);
    }
    __syncthreads();

    const int tx = t & 15, ty = t >> 4;
    const int r0 = ty * 4, c0 = tx * 4;
    float acc[4][4];
    #pragma unroll
    for (int i = 0; i < 4; ++i)
        #pragma unroll
        for (int j = 0; j < 4; ++j) acc[i][j] = 0.f;

    #pragma unroll 4
    for (int k = 0; k < CC; ++k) {
        float4 b = *(float4*)&Bs[k][c0];
        float a0 = As[r0][k], a1 = As[r0 + 1][k], a2 = As[r0 + 2][k], a3 = As[r0 + 3][k];
        acc[0][0] += a0 * b.x; acc[0][1] += a0 * b.y; acc[0][2] += a0 * b.z; acc[0][3] += a0 * b.w;
        acc[1][0] += a1 * b.x; acc[1][1] += a1 * b.y; acc[1][2] += a1 * b.z; acc[1][3] += a1 * b.w;
        acc[2][0] += a2 * b.x; acc[2][1] += a2 * b.y; acc[2][2] += a2 * b.z; acc[2][3] += a2 * b.w;
        acc[3][0] += a3 * b.x; acc[3][1] += a3 * b.y; acc[3][2] += a3 * b.z; acc[3][3] += a3 * b.w;
    }

    #pragma unroll
    for (int i = 0; i < 4; ++i) {
        int m = m0 + r0 + i;
        #pragma unroll
        for (int j = 0; j < 4; ++j) {
            int n = n0 + c0 + j;
            out[(size_t)m * CC + n] = acc[i][j] + bias[n];
        }
    }
}

// ---------------------------------------------------------------------------
extern "C" void kernel_launch(void* const* d_in, const int* in_sizes, int n_in,
                              void* d_out, int out_size, void* d_ws, size_t ws_size,
                              hipStream_t stream) {
    const float* pair_rep = (const float*)d_in[0];
    const float* dm       = (const float*)d_in[1];
    const float* Wqkv     = (const float*)d_in[2];
    const float* bqkv     = (const float*)d_in[3];
    const float* Wout     = (const float*)d_in[4];
    const float* bout     = (const float*)d_in[5];
    const float* dscale   = (const float*)d_in[6];
    const int*   mask     = (const int*)d_in[7];
    float* out = (float*)d_out;

    // ws layout: biasM [256*256 f32 = 256KB] | qkv [65536*384 bf16] | attn [65536*128 bf16]
    float* biasM = (float*)d_ws;
    __hip_bfloat16* qkv  = (__hip_bfloat16*)((char*)d_ws + (size_t)NN * NN * 4);
    __hip_bfloat16* attn = qkv + (size_t)65536 * 384;

    dim3 blk(256);
    bias_kernel<<<dim3(256), blk, 0, stream>>>(dm, mask, dscale, biasM);
    qkv_gemm_kernel<<<dim3(1024, 6), blk, 0, stream>>>(pair_rep, Wqkv, bqkv, qkv);
    attn_mfma_kernel<<<dim3(1024), blk, 0, stream>>>(qkv, biasM, attn);
    out_gemm_kernel<<<dim3(1024, 2), blk, 0, stream>>>(attn, Wout, bout, out);
}

// Round 3
// 179.528 us; speedup vs baseline: 3.2971x; 1.4420x over previous
//
#include <hip/hip_runtime.h>
#include <hip/hip_bf16.h>
#include <math.h>

#define NN 256
#define CC 128
#define HH 4
#define DD 32

typedef uint4 u128;
typedef __bf16 bf16x8 __attribute__((ext_vector_type(8)));
typedef float f32x4 __attribute__((ext_vector_type(4)));

// ---------------------------------------------------------------------------
// K0 prep: biasM[j,k] = mask ? -inf : dscale*dm ; Wt_qkv[n][k] = bf16(Wqkv[k][n]);
//          Wt_out[n][k] = bf16(Wout[k][n])
// grid 512x256: blocks [0,256) biasM, [256,448) Wt_qkv, [448,512) Wt_out
// ---------------------------------------------------------------------------
__global__ __launch_bounds__(256) void prep_kernel(
    const float* __restrict__ dm, const int* __restrict__ mask,
    const float* __restrict__ dscale,
    const float* __restrict__ Wqkv, const float* __restrict__ Wout,
    float* __restrict__ biasM,
    __hip_bfloat16* __restrict__ Wt_qkv, __hip_bfloat16* __restrict__ Wt_out)
{
    const int b = blockIdx.x, t = threadIdx.x;
    if (b < 256) {
        int idx = b * 256 + t;
        biasM[idx] = mask[idx] ? -INFINITY : dscale[0] * dm[idx];
    } else if (b < 448) {
        int idx = (b - 256) * 256 + t;         // [0, 49152)
        int n = idx >> 7, k = idx & 127;
        Wt_qkv[idx] = __float2bfloat16(Wqkv[(size_t)k * 384 + n]);
    } else {
        int idx = (b - 448) * 256 + t;         // [0, 16384)
        int n = idx >> 7, k = idx & 127;
        Wt_out[idx] = __float2bfloat16(Wout[(size_t)k * CC + n]);
    }
}

// ---------------------------------------------------------------------------
// K1: qkv = pair_rep @ Wqkv + bqkv  (MFMA bf16, fp32 acc, bf16 out)
// 128m x 96n tile, grid (512,4), 256 thr. Wave w: m-half (w&1), n-third... (w>>1)
// wave-tile 64x48 = 4 mt x 3 nt, K=128 = 4 ksteps of 32 -> 48 MFMAs/wave.
// ---------------------------------------------------------------------------
__global__ __launch_bounds__(256) void qkv_mfma_kernel(
    const float* __restrict__ A,              // [65536,128] fp32
    const __hip_bfloat16* __restrict__ Bt,    // [384,128] bf16 (transposed W)
    const float* __restrict__ bias,           // [384]
    __hip_bfloat16* __restrict__ out)         // [65536,384]
{
    __shared__ __align__(16) __hip_bfloat16 As[128][136];
    __shared__ __align__(16) __hip_bfloat16 Bs[96][136];
    const int t = threadIdx.x;
    const int m0 = blockIdx.x * 128;
    const int n0 = blockIdx.y * 96;

    #pragma unroll
    for (int it = 0; it < 16; ++it) {          // A: 128 rows x 32 chunks of 4 fp32
        int idx = it * 256 + t;
        int r = idx >> 5, c4 = (idx & 31) * 4;
        float4 v = *(const float4*)(A + (size_t)(m0 + r) * CC + c4);
        __align__(8) __hip_bfloat16 p[4];
        p[0] = __float2bfloat16(v.x); p[1] = __float2bfloat16(v.y);
        p[2] = __float2bfloat16(v.z); p[3] = __float2bfloat16(v.w);
        *(uint2*)&As[r][c4] = *(uint2*)p;
    }
    #pragma unroll
    for (int it = 0; it < 6; ++it) {           // B: 96 rows x 16 chunks of 8 bf16
        int idx = it * 256 + t;
        int n = idx >> 4, c8 = (idx & 15) * 8;
        *(u128*)&Bs[n][c8] = *(const u128*)(Bt + (size_t)(n0 + n) * CC + c8);
    }
    __syncthreads();

    const int w = t >> 6, lane = t & 63;
    const int n16 = lane & 15, quad = lane >> 4;
    const int mw = (w & 1) * 64, nw = (w >> 1) * 48;

    bf16x8 af[4][4];                           // [mt][ks]
    #pragma unroll
    for (int mt = 0; mt < 4; ++mt)
        #pragma unroll
        for (int ks = 0; ks < 4; ++ks)
            af[mt][ks] = *(const bf16x8*)&As[mw + mt * 16 + n16][ks * 32 + quad * 8];

    f32x4 acc[4][3];
    #pragma unroll
    for (int mt = 0; mt < 4; ++mt)
        #pragma unroll
        for (int nt = 0; nt < 3; ++nt) acc[mt][nt] = (f32x4){0.f, 0.f, 0.f, 0.f};

    #pragma unroll
    for (int nt = 0; nt < 3; ++nt) {
        bf16x8 bfr[4];
        #pragma unroll
        for (int ks = 0; ks < 4; ++ks)
            bfr[ks] = *(const bf16x8*)&Bs[nw + nt * 16 + n16][ks * 32 + quad * 8];
        #pragma unroll
        for (int ks = 0; ks < 4; ++ks)
            #pragma unroll
            for (int mt = 0; mt < 4; ++mt)
                acc[mt][nt] = __builtin_amdgcn_mfma_f32_16x16x32_bf16(af[mt][ks], bfr[ks], acc[mt][nt], 0, 0, 0);
    }

    #pragma unroll
    for (int nt = 0; nt < 3; ++nt) {
        int n = n0 + nw + nt * 16 + n16;
        float bv = bias[n];
        #pragma unroll
        for (int mt = 0; mt < 4; ++mt) {
            int mrow = m0 + mw + mt * 16 + quad * 4;
            #pragma unroll
            for (int r = 0; r < 4; ++r)
                out[(size_t)(mrow + r) * 384 + n] = __float2bfloat16(acc[mt][nt][r] + bv);
        }
    }
}

// ---------------------------------------------------------------------------
// K2: MFMA attention (unchanged from round 2)
// ---------------------------------------------------------------------------
__global__ __launch_bounds__(256) void attn_mfma_kernel(
    const __hip_bfloat16* __restrict__ qkv,   // [65536,384]
    const float* __restrict__ biasM,          // [256,256]
    __hip_bfloat16* __restrict__ attn_out)    // [65536,128]
{
    __shared__ __align__(16) __hip_bfloat16 Ks[NN][40];
    __shared__ __align__(16) __hip_bfloat16 VTs[DD][264];
    __shared__ __align__(16) __hip_bfloat16 Ps[4][16][264];

    const int bi = blockIdx.x;
    const int i = bi >> 2, h = bi & 3;
    const int t = threadIdx.x;
    const float scale = 0.17677669529663687f;

    {
        const __hip_bfloat16* base = qkv + (size_t)(i * NN + t) * 384 + h * DD;
        const u128* ksrc = (const u128*)(base + CC);
        const u128* vsrc = (const u128*)(base + 2 * CC);
        u128* kdst = (u128*)&Ks[t][0];
        u128 vr[4];
        #pragma unroll
        for (int u = 0; u < 4; ++u) { kdst[u] = ksrc[u]; vr[u] = vsrc[u]; }
        const __hip_bfloat16* vh = (const __hip_bfloat16*)vr;
        #pragma unroll
        for (int d = 0; d < DD; ++d) VTs[d][t] = vh[d];
    }
    __syncthreads();

    const int w = t >> 6, lane = t & 63;
    const int n16 = lane & 15, quad = lane >> 4;

    for (int jt = 0; jt < 4; ++jt) {
        const int j0 = w * 64 + jt * 16;

        bf16x8 qa = *(const bf16x8*)(qkv + (size_t)(i * NN + j0 + n16) * 384 + h * DD + quad * 8);

        f32x4 s[16];
        #pragma unroll
        for (int kt = 0; kt < 16; ++kt) {
            bf16x8 kb = *(const bf16x8*)&Ks[kt * 16 + n16][quad * 8];
            s[kt] = __builtin_amdgcn_mfma_f32_16x16x32_bf16(qa, kb, (f32x4){0.f, 0.f, 0.f, 0.f}, 0, 0, 0);
        }

        float inv_sum[4];
        #pragma unroll
        for (int r = 0; r < 4; ++r) {
            const float* brow = biasM + (size_t)(j0 + quad * 4 + r) * NN + n16;
            float m = -INFINITY;
            #pragma unroll
            for (int kt = 0; kt < 16; ++kt) {
                float v = s[kt][r] * scale + brow[kt * 16];
                s[kt][r] = v;
                m = fmaxf(m, v);
            }
            m = fmaxf(m, __shfl_xor(m, 1));
            m = fmaxf(m, __shfl_xor(m, 2));
            m = fmaxf(m, __shfl_xor(m, 4));
            m = fmaxf(m, __shfl_xor(m, 8));
            float sum = 0.f;
            #pragma unroll
            for (int kt = 0; kt < 16; ++kt) {
                float p = __expf(s[kt][r] - m);
                sum += p;
                Ps[w][quad * 4 + r][kt * 16 + n16] = __float2bfloat16(p);
            }
            sum += __shfl_xor(sum, 1);
            sum += __shfl_xor(sum, 2);
            sum += __shfl_xor(sum, 4);
            sum += __shfl_xor(sum, 8);
            inv_sum[r] = 1.0f / sum;
        }

        f32x4 o[2] = {(f32x4){0.f, 0.f, 0.f, 0.f}, (f32x4){0.f, 0.f, 0.f, 0.f}};
        #pragma unroll
        for (int c = 0; c < 8; ++c) {
            bf16x8 pa = *(const bf16x8*)&Ps[w][n16][c * 32 + quad * 8];
            #pragma unroll
            for (int dt = 0; dt < 2; ++dt) {
                bf16x8 vb = *(const bf16x8*)&VTs[dt * 16 + n16][c * 32 + quad * 8];
                o[dt] = __builtin_amdgcn_mfma_f32_16x16x32_bf16(pa, vb, o[dt], 0, 0, 0);
            }
        }

        #pragma unroll
        for (int r = 0; r < 4; ++r) {
            __hip_bfloat16* orow = attn_out + (size_t)(i * NN + j0 + quad * 4 + r) * CC + h * DD;
            #pragma unroll
            for (int dt = 0; dt < 2; ++dt)
                orow[dt * 16 + n16] = __float2bfloat16(o[dt][r] * inv_sum[r]);
        }
    }
}

// ---------------------------------------------------------------------------
// K3: out = attn_out @ Wout + bout  (MFMA bf16, fp32 out)
// 128x128 tile, grid (512), wave-tile 64x64 -> 64 MFMAs/wave.
// ---------------------------------------------------------------------------
__global__ __launch_bounds__(256) void out_mfma_kernel(
    const __hip_bfloat16* __restrict__ A,     // [65536,128] bf16
    const __hip_bfloat16* __restrict__ Bt,    // [128,128] bf16 (transposed W)
    const float* __restrict__ bias,           // [128]
    float* __restrict__ out)                  // [65536,128]
{
    __shared__ __align__(16) __hip_bfloat16 As[128][136];
    __shared__ __align__(16) __hip_bfloat16 Bs[128][136];
    const int t = threadIdx.x;
    const int m0 = blockIdx.x * 128;

    #pragma unroll
    for (int it = 0; it < 8; ++it) {           // A: 128 x 16 chunks of 8 bf16
        int idx = it * 256 + t;
        int r = idx >> 4, c8 = (idx & 15) * 8;
        *(u128*)&As[r][c8] = *(const u128*)(A + (size_t)(m0 + r) * CC + c8);
    }
    #pragma unroll
    for (int it = 0; it < 8; ++it) {           // B: 128 x 16 chunks
        int idx = it * 256 + t;
        int n = idx >> 4, c8 = (idx & 15) * 8;
        *(u128*)&Bs[n][c8] = *(const u128*)(Bt + (size_t)n * CC + c8);
    }
    __syncthreads();

    const int w = t >> 6, lane = t & 63;
    const int n16 = lane & 15, quad = lane >> 4;
    const int mw = (w & 1) * 64, nw = (w >> 1) * 64;

    bf16x8 af[4][4];
    #pragma unroll
    for (int mt = 0; mt < 4; ++mt)
        #pragma unroll
        for (int ks = 0; ks < 4; ++ks)
            af[mt][ks] = *(const bf16x8*)&As[mw + mt * 16 + n16][ks * 32 + quad * 8];

    f32x4 acc[4][4];
    #pragma unroll
    for (int mt = 0; mt < 4; ++mt)
        #pragma unroll
        for (int nt = 0; nt < 4; ++nt) acc[mt][nt] = (f32x4){0.f, 0.f, 0.f, 0.f};

    #pragma unroll
    for (int nt = 0; nt < 4; ++nt) {
        bf16x8 bfr[4];
        #pragma unroll
        for (int ks = 0; ks < 4; ++ks)
            bfr[ks] = *(const bf16x8*)&Bs[nw + nt * 16 + n16][ks * 32 + quad * 8];
        #pragma unroll
        for (int ks = 0; ks < 4; ++ks)
            #pragma unroll
            for (int mt = 0; mt < 4; ++mt)
                acc[mt][nt] = __builtin_amdgcn_mfma_f32_16x16x32_bf16(af[mt][ks], bfr[ks], acc[mt][nt], 0, 0, 0);
    }

    #pragma unroll
    for (int nt = 0; nt < 4; ++nt) {
        int n = nw + nt * 16 + n16;
        float bv = bias[n];
        #pragma unroll
        for (int mt = 0; mt < 4; ++mt) {
            int mrow = m0 + mw + mt * 16 + quad * 4;
            #pragma unroll
            for (int r = 0; r < 4; ++r)
                out[(size_t)(mrow + r) * CC + n] = acc[mt][nt][r] + bv;
        }
    }
}

// ---------------------------------------------------------------------------
extern "C" void kernel_launch(void* const* d_in, const int* in_sizes, int n_in,
                              void* d_out, int out_size, void* d_ws, size_t ws_size,
                              hipStream_t stream) {
    const float* pair_rep = (const float*)d_in[0];
    const float* dm       = (const float*)d_in[1];
    const float* Wqkv     = (const float*)d_in[2];
    const float* bqkv     = (const float*)d_in[3];
    const float* Wout     = (const float*)d_in[4];
    const float* bout     = (const float*)d_in[5];
    const float* dscale   = (const float*)d_in[6];
    const int*   mask     = (const int*)d_in[7];
    float* out = (float*)d_out;

    // ws: biasM[256KB] | Wt_qkv[96KB] | Wt_out[32KB] | qkv[48MB] | attn[16MB]
    char* p = (char*)d_ws;
    float* biasM = (float*)p;                 p += (size_t)NN * NN * 4;
    __hip_bfloat16* Wt_qkv = (__hip_bfloat16*)p;  p += (size_t)384 * CC * 2;
    __hip_bfloat16* Wt_out = (__hip_bfloat16*)p;  p += (size_t)CC * CC * 2;
    __hip_bfloat16* qkv  = (__hip_bfloat16*)p;    p += (size_t)65536 * 384 * 2;
    __hip_bfloat16* attn = (__hip_bfloat16*)p;

    dim3 blk(256);
    prep_kernel<<<dim3(512), blk, 0, stream>>>(dm, mask, dscale, Wqkv, Wout, biasM, Wt_qkv, Wt_out);
    qkv_mfma_kernel<<<dim3(512, 4), blk, 0, stream>>>(pair_rep, Wt_qkv, bqkv, qkv);
    attn_mfma_kernel<<<dim3(1024), blk, 0, stream>>>(qkv, biasM, attn);
    out_mfma_kernel<<<dim3(512), blk, 0, stream>>>(attn, Wt_out, bout, out);
}